// Round 1
// baseline (28.474 us; speedup 1.0000x reference)
//
#include <hip/hip_runtime.h>

// out[k] = (sum_j sigmoid(s*(x[j]-x[k])) + 0.5) / N,  s = SCALE/std(triu diff matrix)
// std closed form: var = (N*sum(x^2) - sum(x)^2 - S^2/N^2) / (N^2-1),
//                  S = sum_k x[k]*(2k - N + 1)

constexpr int   N      = 1024;
constexpr float SCALE  = 6.8f;
constexpr float LOG2E  = 1.4426950408889634f;

__global__ __launch_bounds__(256) void softrank_kernel(
    const float* __restrict__ in, float* __restrict__ out)
{
    const int row  = blockIdx.y;
    const int tid  = threadIdx.x;
    const int lane = tid & 63;
    const int wave = tid >> 6;

    __shared__ float xs[N];
    __shared__ float wred[4][3];

    const float* x = in + row * N;

    // stage full row into LDS, 4 elems/thread, vectorized
    float4 v = reinterpret_cast<const float4*>(x)[tid];
    reinterpret_cast<float4*>(xs)[tid] = v;

    // O(N) stats partials
    const int k0 = tid * 4;
    float psum = v.x + v.y + v.z + v.w;
    float psq  = v.x * v.x + v.y * v.y + v.z * v.z + v.w * v.w;
    float pw   = v.x * (float)(2 * k0       - (N - 1))
               + v.y * (float)(2 * (k0 + 1) - (N - 1))
               + v.z * (float)(2 * (k0 + 2) - (N - 1))
               + v.w * (float)(2 * (k0 + 3) - (N - 1));

    #pragma unroll
    for (int off = 32; off >= 1; off >>= 1) {
        psum += __shfl_down(psum, off, 64);
        psq  += __shfl_down(psq,  off, 64);
        pw   += __shfl_down(pw,   off, 64);
    }
    if (lane == 0) {
        wred[wave][0] = psum;
        wred[wave][1] = psq;
        wred[wave][2] = pw;
    }
    __syncthreads();   // also covers the xs[] staging

    const float sum = wred[0][0] + wred[1][0] + wred[2][0] + wred[3][0];
    const float sq  = wred[0][1] + wred[1][1] + wred[2][1] + wred[3][1];
    const float sw  = wred[0][2] + wred[1][2] + wred[2][2] + wred[3][2];

    const float n2     = (float)N * (float)N;
    const float pairSq = (float)N * sq - sum * sum;
    const float var    = (pairSq - (sw * sw) / n2) / (n2 - 1.0f);
    const float s      = SCALE * __builtin_amdgcn_rsqf(var);  // SCALE / std
    const float c      = s * LOG2E;

    // each thread owns one output element k
    const int   k   = blockIdx.x * 256 + tid;
    const float cxk = c * xs[k];

    // sigmoid(s*(x[j]-x[k])) = rcp(1 + exp2(c*(x[k]-x[j]))) = rcp(1 + exp2(cxk - c*x[j]))
    float acc = 0.0f;
    #pragma unroll 8
    for (int j = 0; j < N; ++j) {
        const float t = __builtin_amdgcn_exp2f(cxk - c * xs[j]);  // fma + trans
        acc += __builtin_amdgcn_rcpf(1.0f + t);
    }

    out[row * N + k] = (acc + 0.5f) * (1.0f / (float)N);
}

extern "C" void kernel_launch(void* const* d_in, const int* in_sizes, int n_in,
                              void* d_out, int out_size, void* d_ws, size_t ws_size,
                              hipStream_t stream)
{
    const float* in  = (const float*)d_in[0];
    float*       out = (float*)d_out;

    const int total = in_sizes[0];      // B * N
    const int Brows = total / N;        // 64

    dim3 grid(N / 256, Brows);          // (4, 64) = 256 blocks
    softrank_kernel<<<grid, 256, 0, stream>>>(in, out);
}

// Round 2
// 19.439 us; speedup vs baseline: 1.4648x; 1.4648x over previous
//
#include <hip/hip_runtime.h>

// out[k] = (sum_j sigmoid(s*(x[j]-x[k])) + 0.5) / N,  s = SCALE/std(triu diff matrix)
// std closed form: var = (N*sum(x^2) - sum(x)^2 - S^2/N^2) / (N^2-1),
//                  S = sum_k x[k]*(2k - N + 1)
//
// Block = 256 threads (4 waves). Each block owns 64 outputs (k = bx*64 + lane);
// wave w computes the partial sum over j in [w*256, w*256+256), LDS-combine.
// => grid 1024 blocks = 4096 waves = 4 waves/SIMD (latency hiding), and the
// serial accumulator chain is split 4 ways per thread on top.

constexpr int   N      = 1024;
constexpr int   KPB    = 64;          // outputs per block
constexpr int   JCHUNK = N / 4;       // j's per wave
constexpr float SCALE  = 6.8f;
constexpr float LOG2E  = 1.4426950408889634f;

__global__ __launch_bounds__(256) void softrank_kernel(
    const float* __restrict__ in, float* __restrict__ out)
{
    const int row  = blockIdx.y;
    const int tid  = threadIdx.x;
    const int lane = tid & 63;
    const int wave = tid >> 6;

    __shared__ float xs[N];           // row, later scaled by c*log2e
    __shared__ float wred[4][3];
    __shared__ float part[4][KPB];

    const float* x = in + row * N;

    // stage full row into LDS, 4 elems/thread, vectorized
    float4 v = reinterpret_cast<const float4*>(x)[tid];
    reinterpret_cast<float4*>(xs)[tid] = v;

    // O(N) stats partials
    const int k0 = tid * 4;
    float psum = v.x + v.y + v.z + v.w;
    float psq  = v.x * v.x + v.y * v.y + v.z * v.z + v.w * v.w;
    float pw   = v.x * (float)(2 * k0       - (N - 1))
               + v.y * (float)(2 * (k0 + 1) - (N - 1))
               + v.z * (float)(2 * (k0 + 2) - (N - 1))
               + v.w * (float)(2 * (k0 + 3) - (N - 1));

    #pragma unroll
    for (int off = 32; off >= 1; off >>= 1) {
        psum += __shfl_down(psum, off, 64);
        psq  += __shfl_down(psq,  off, 64);
        pw   += __shfl_down(pw,   off, 64);
    }
    if (lane == 0) {
        wred[wave][0] = psum;
        wred[wave][1] = psq;
        wred[wave][2] = pw;
    }
    __syncthreads();   // also covers the xs[] staging

    const float sum = wred[0][0] + wred[1][0] + wred[2][0] + wred[3][0];
    const float sq  = wred[0][1] + wred[1][1] + wred[2][1] + wred[3][1];
    const float sw  = wred[0][2] + wred[1][2] + wred[2][2] + wred[3][2];

    const float n2     = (float)N * (float)N;
    const float pairSq = (float)N * sq - sum * sum;
    const float var    = (pairSq - (sw * sw) / n2) / (n2 - 1.0f);
    const float s      = SCALE * __builtin_amdgcn_rsqf(var);  // SCALE / std
    const float c      = s * LOG2E;

    // this thread's output (all 4 waves cover the same 64 k's)
    const int   k   = blockIdx.x * KPB + lane;
    const float cxk = c * xs[k];          // read RAW xs before in-place scale

    __syncthreads();
    // scale row in place: xs[i] = c * x[i]
    reinterpret_cast<float4*>(xs)[tid] =
        make_float4(v.x * c, v.y * c, v.z * c, v.w * c);
    __syncthreads();

    // sigmoid(s*(x[j]-x[k])) = rcp(1 + exp2(cxk - c*x[j]))
    float a0 = 0.0f, a1 = 0.0f, a2 = 0.0f, a3 = 0.0f;
    const int j0 = wave * JCHUNK;
    #pragma unroll 4
    for (int j = j0; j < j0 + JCHUNK; j += 4) {
        const float4 xj = *reinterpret_cast<const float4*>(&xs[j]);  // ds_read_b128 broadcast
        const float t0 = __builtin_amdgcn_exp2f(cxk - xj.x);
        const float t1 = __builtin_amdgcn_exp2f(cxk - xj.y);
        const float t2 = __builtin_amdgcn_exp2f(cxk - xj.z);
        const float t3 = __builtin_amdgcn_exp2f(cxk - xj.w);
        a0 += __builtin_amdgcn_rcpf(1.0f + t0);
        a1 += __builtin_amdgcn_rcpf(1.0f + t1);
        a2 += __builtin_amdgcn_rcpf(1.0f + t2);
        a3 += __builtin_amdgcn_rcpf(1.0f + t3);
    }
    part[wave][lane] = (a0 + a1) + (a2 + a3);
    __syncthreads();

    if (tid < KPB) {
        const float r = part[0][tid] + part[1][tid] + part[2][tid] + part[3][tid];
        out[row * N + blockIdx.x * KPB + tid] = (r + 0.5f) * (1.0f / (float)N);
    }
}

extern "C" void kernel_launch(void* const* d_in, const int* in_sizes, int n_in,
                              void* d_out, int out_size, void* d_ws, size_t ws_size,
                              hipStream_t stream)
{
    const float* in  = (const float*)d_in[0];
    float*       out = (float*)d_out;

    const int total = in_sizes[0];      // B * N
    const int Brows = total / N;        // 64

    dim3 grid(N / KPB, Brows);          // (16, 64) = 1024 blocks
    softrank_kernel<<<grid, 256, 0, stream>>>(in, out);
}

// Round 3
// 18.342 us; speedup vs baseline: 1.5524x; 1.0598x over previous
//
#include <hip/hip_runtime.h>

// out[k] = (sum_j sigmoid(s*(x[j]-x[k])) + 0.5) / N,  s = SCALE/std(triu diff matrix)
// std closed form: var = (N*sum(x^2) - sum(x)^2 - S^2/N^2) / (N^2-1),
//                  S = sum_k x[k]*(2k - N + 1)
//
// R2: quad-batched reciprocal. We only need SUM of sigmoids, so
//   1/a + 1/b + 1/c + 1/d = ((a+b)*cd + (c+d)*ab) * rcp(ab*cd)
// -> 1 v_rcp per 4 elements instead of 1 per element (trans pipe is the
// binder at ~16 cy/wave64 per trans op; 2.0 -> 1.25 trans/elem).
// t clamped to <=4096 so products stay finite (sigma trunc err <= 2.4e-4).

constexpr int   N      = 1024;
constexpr int   KPB    = 64;          // outputs per block
constexpr int   JCHUNK = N / 4;       // j's per wave
constexpr float SCALE  = 6.8f;
constexpr float LOG2E  = 1.4426950408889634f;

__device__ __forceinline__ float quadSig(float cxk, float4 xj)
{
    // t_i = 2^(c*(x_k - x_j))  (sigmoid arg in log2 domain, pre-scaled row)
    float t0 = __builtin_amdgcn_exp2f(cxk - xj.x);
    float t1 = __builtin_amdgcn_exp2f(cxk - xj.y);
    float t2 = __builtin_amdgcn_exp2f(cxk - xj.z);
    float t3 = __builtin_amdgcn_exp2f(cxk - xj.w);
    t0 = fminf(t0, 4096.0f);
    t1 = fminf(t1, 4096.0f);
    t2 = fminf(t2, 4096.0f);
    t3 = fminf(t3, 4096.0f);
    const float a = t0 + 1.0f, b = t1 + 1.0f;
    const float c = t2 + 1.0f, d = t3 + 1.0f;
    const float ab  = a * b;
    const float cd  = c * d;
    const float num = (a + b) * cd + (c + d) * ab;
    return num * __builtin_amdgcn_rcpf(ab * cd);
}

__global__ __launch_bounds__(256) void softrank_kernel(
    const float* __restrict__ in, float* __restrict__ out)
{
    const int row  = blockIdx.y;
    const int tid  = threadIdx.x;
    const int lane = tid & 63;
    const int wave = tid >> 6;

    __shared__ float xs[N];           // row, later scaled by c = s*log2(e)
    __shared__ float wred[4][3];
    __shared__ float part[4][KPB];

    const float* x = in + row * N;

    // stage full row into LDS, 4 elems/thread, vectorized
    float4 v = reinterpret_cast<const float4*>(x)[tid];
    reinterpret_cast<float4*>(xs)[tid] = v;

    // O(N) stats partials
    const int k0 = tid * 4;
    float psum = v.x + v.y + v.z + v.w;
    float psq  = v.x * v.x + v.y * v.y + v.z * v.z + v.w * v.w;
    float pw   = v.x * (float)(2 * k0       - (N - 1))
               + v.y * (float)(2 * (k0 + 1) - (N - 1))
               + v.z * (float)(2 * (k0 + 2) - (N - 1))
               + v.w * (float)(2 * (k0 + 3) - (N - 1));

    #pragma unroll
    for (int off = 32; off >= 1; off >>= 1) {
        psum += __shfl_down(psum, off, 64);
        psq  += __shfl_down(psq,  off, 64);
        pw   += __shfl_down(pw,   off, 64);
    }
    if (lane == 0) {
        wred[wave][0] = psum;
        wred[wave][1] = psq;
        wred[wave][2] = pw;
    }
    __syncthreads();   // also covers the xs[] staging

    const float sum = wred[0][0] + wred[1][0] + wred[2][0] + wred[3][0];
    const float sq  = wred[0][1] + wred[1][1] + wred[2][1] + wred[3][1];
    const float sw  = wred[0][2] + wred[1][2] + wred[2][2] + wred[3][2];

    const float n2     = (float)N * (float)N;
    const float pairSq = (float)N * sq - sum * sum;
    const float var    = (pairSq - (sw * sw) / n2) / (n2 - 1.0f);
    const float s      = SCALE * __builtin_amdgcn_rsqf(var);  // SCALE / std
    const float c      = s * LOG2E;

    // this thread's output (all 4 waves cover the same 64 k's)
    const int   k   = blockIdx.x * KPB + lane;
    const float cxk = c * xs[k];          // read RAW xs before in-place scale

    __syncthreads();
    // scale row in place: xs[i] = c * x[i]
    reinterpret_cast<float4*>(xs)[tid] =
        make_float4(v.x * c, v.y * c, v.z * c, v.w * c);
    __syncthreads();

    // acc = sum_j 1/(1 + 2^(cxk - c*x[j])), two independent quad chains
    float acc0 = 0.0f, acc1 = 0.0f;
    const int q0 = wave * (JCHUNK / 4);           // quad index base
    const float4* xs4 = reinterpret_cast<const float4*>(xs);
    #pragma unroll 4
    for (int q = q0; q < q0 + JCHUNK / 4; q += 2) {
        acc0 += quadSig(cxk, xs4[q]);
        acc1 += quadSig(cxk, xs4[q + 1]);
    }
    part[wave][lane] = acc0 + acc1;
    __syncthreads();

    if (tid < KPB) {
        const float r = part[0][tid] + part[1][tid] + part[2][tid] + part[3][tid];
        out[row * N + blockIdx.x * KPB + tid] = (r + 0.5f) * (1.0f / (float)N);
    }
}

extern "C" void kernel_launch(void* const* d_in, const int* in_sizes, int n_in,
                              void* d_out, int out_size, void* d_ws, size_t ws_size,
                              hipStream_t stream)
{
    const float* in  = (const float*)d_in[0];
    float*       out = (float*)d_out;

    const int total = in_sizes[0];      // B * N
    const int Brows = total / N;        // 64

    dim3 grid(N / KPB, Brows);          // (16, 64) = 1024 blocks
    softrank_kernel<<<grid, 256, 0, stream>>>(in, out);
}